// Round 6
// baseline (484.620 us; speedup 1.0000x reference)
//
#include <hip/hip_runtime.h>
#include <hip/hip_bf16.h>

// GCN 3-layer forward, MI355X. Round 6:
//  - Two-phase CSR build. r5's single-phase fill wrote node-major CSR whose
//    128B lines are dirtied by 8 XCDs -> 98.7MB writeback for 12.8MB payload.
//    Phase A scatters into a replica-major temp (lines single-XCD-owned,
//    L2-resident). Phase B copies temp -> node-major CSR with destination-
//    ordered fully-coalesced writes (8 lanes per node, shfl prefix).
//    Final CSR layout identical to r5 => gather untouched semantics.
//  - Gather neighbor loop unrolled 4 -> 8 (latency-bound, VALUBusy 28%).
//
// Pipeline (recomputed every call => graph-replay safe):
//  1. memset hist; k_edge_pass1R: hist[r*N+dst] += (1<<40)+attr*2^32 (r=blk&7)
//  2. k_degcnt: dinv = rsqrt(1+sum_r w); cnt = sum_r c
//  3. scan cnt(N) -> rowptr ; scan hist counts(8N, r-major) -> ptrT/cursorT
//  4. k_fill_temp: tempcsr[atomicAdd(cursorT[r*N+dst])] = {src,w}  (XCD-local)
//  5. k_permute: csr[rowptr[i] + pre_r + k] = tempcsr[segment(r,i) + k]
//  6. mfma gemm1 -> gather1 -> BN1 -> mfma gemm2(BN fused) -> gather2 -> BN2
//     -> dotW3 -> gather3(out)

#define HID 128
#define BN_EPS 1e-5f

typedef __attribute__((ext_vector_type(8))) short bf16x8;
typedef __attribute__((ext_vector_type(4))) float f32x4;

static inline size_t alignup(size_t x){ return (x + 255) & ~(size_t)255; }

// ---------------- graph preprocessing ----------------

__global__ void k_edge_pass1R(const int* __restrict__ ei, const float* __restrict__ attr,
                              unsigned long long* __restrict__ hist, int N, int E){
  int e = blockIdx.x*256 + threadIdx.x;
  if (e >= E) return;
  int r = blockIdx.x & 7;
  int dst = ei[E + e];
  unsigned long long pk = (1ULL << 40)
                        + (unsigned long long)((double)attr[e] * 4294967296.0);
  atomicAdd(&hist[(size_t)r*N + dst], pk);
}

__global__ void k_degcnt(const unsigned long long* __restrict__ hist,
                         float* __restrict__ dinv, int* __restrict__ cnt, int N){
  int i = blockIdx.x*256 + threadIdx.x;
  if (i >= N) return;
  unsigned long long wsum = 0; int c = 0;
  #pragma unroll
  for (int r = 0; r < 8; ++r){
    unsigned long long h = hist[(size_t)r*N + i];
    wsum += h & ((1ULL << 40) - 1);
    c += (int)(h >> 40);
  }
  float deg = 1.0f + (float)((double)wsum * 2.3283064365386963e-10);  // *2^-32
  dinv[i] = 1.0f / sqrtf(deg);
  cnt[i] = c;
}

// block-local exclusive scan of int array
__global__ void k_scanA_int(const int* __restrict__ in, int* outv, int* bsum, int n){
  __shared__ int tmp[256];
  int i = blockIdx.x*256 + threadIdx.x;
  int v = (i < n) ? in[i] : 0;
  tmp[threadIdx.x] = v;
  __syncthreads();
  #pragma unroll
  for (int d = 1; d < 256; d <<= 1){
    int t = (threadIdx.x >= d) ? tmp[threadIdx.x - d] : 0;
    __syncthreads();
    tmp[threadIdx.x] += t;
    __syncthreads();
  }
  if (i < n) outv[i] = tmp[threadIdx.x] - v;
  if (threadIdx.x == 255) bsum[blockIdx.x] = tmp[255];
}

// block-local exclusive scan over hist counts (hi 24 bits)
__global__ void k_scanA_hist(const unsigned long long* __restrict__ hist,
                             int* outv, int* bsum, int n8){
  __shared__ int tmp[256];
  int i = blockIdx.x*256 + threadIdx.x;
  int v = (i < n8) ? (int)(hist[i] >> 40) : 0;
  tmp[threadIdx.x] = v;
  __syncthreads();
  #pragma unroll
  for (int d = 1; d < 256; d <<= 1){
    int t = (threadIdx.x >= d) ? tmp[threadIdx.x - d] : 0;
    __syncthreads();
    tmp[threadIdx.x] += t;
    __syncthreads();
  }
  if (i < n8) outv[i] = tmp[threadIdx.x] - v;
  if (threadIdx.x == 255) bsum[blockIdx.x] = tmp[255];
}

// single-block sequential-chunk exclusive scan of nb block sums (nb <= 4096)
__global__ void k_scanB_big(int* bsum, int nb){
  __shared__ int tmp[512];
  __shared__ int carry;
  if (threadIdx.x == 0) carry = 0;
  __syncthreads();
  for (int base = 0; base < nb; base += 512){
    int idx = base + threadIdx.x;
    int v = (idx < nb) ? bsum[idx] : 0;
    tmp[threadIdx.x] = v;
    __syncthreads();
    #pragma unroll
    for (int d = 1; d < 512; d <<= 1){
      int t = (threadIdx.x >= d) ? tmp[threadIdx.x - d] : 0;
      __syncthreads();
      tmp[threadIdx.x] += t;
      __syncthreads();
    }
    int total = tmp[511];
    if (idx < nb) bsum[idx] = tmp[threadIdx.x] - v + carry;
    __syncthreads();
    if (threadIdx.x == 0) carry += total;
    __syncthreads();
  }
}

__global__ void k_scanC_rowptr(int* rowptr, const int* __restrict__ bsum, int n){
  int i = blockIdx.x*256 + threadIdx.x;
  if (i < n) rowptr[i] += bsum[blockIdx.x];
}

__global__ void k_scanC_temp(int* ptrT, int* cursorT, const int* __restrict__ bsum,
                             int n8, int E){
  int i = blockIdx.x*256 + threadIdx.x;
  if (i < n8){
    int v = ptrT[i] + bsum[blockIdx.x];
    ptrT[i] = v;
    cursorT[i] = v;
  }
  if (i == 0) ptrT[n8] = E;   // sentinel
}

__global__ void k_fill_temp(const int* __restrict__ ei, const float* __restrict__ attr,
                            const float* __restrict__ dinv, int* __restrict__ cursorT,
                            int2* __restrict__ tempcsr, int N, int E){
  int e = blockIdx.x*256 + threadIdx.x;
  if (e >= E) return;
  int r = blockIdx.x & 7;
  int src = ei[e];
  int dst = ei[E + e];
  int pos = atomicAdd(&cursorT[(size_t)r*N + dst], 1);
  float w = dinv[src] * attr[e] * dinv[dst];
  tempcsr[pos] = make_int2(src, __float_as_int(w));
}

// 8 lanes per node (lane r copies replica-r segment). Writes coalesced,
// single-owner lines; reads scattered into L2/L3-resident temp.
__global__ __launch_bounds__(256) void k_permute(const int2* __restrict__ tempcsr,
    const int* __restrict__ ptrT, const int* __restrict__ rowptr,
    int2* __restrict__ csr, int N){
  int i = blockIdx.x*32 + (threadIdx.x >> 3);
  int r = threadIdx.x & 7;
  if (i >= N) return;
  int s   = ptrT[(size_t)r*N + i];
  int len = ptrT[(size_t)r*N + i + 1] - s;
  // exclusive prefix of len over the 8-lane group
  int incl = len;
  #pragma unroll
  for (int d = 1; d < 8; d <<= 1){
    int t = __shfl_up(incl, d, 8);
    if ((threadIdx.x & 7) >= d) incl += t;
  }
  int base = rowptr[i] + (incl - len);
  for (int k = 0; k < len; ++k)
    csr[base + k] = tempcsr[s + k];
}

// ---------------- MFMA GEMM ----------------

static __device__ inline uint2 pack_bf16x4(float4 a){
  __hip_bfloat162 lo = __float22bfloat162_rn({a.x, a.y});
  __hip_bfloat162 hi = __float22bfloat162_rn({a.z, a.w});
  uint2 r;
  r.x = *(unsigned int*)&lo;
  r.y = *(unsigned int*)&hi;
  return r;
}

static __device__ inline unsigned short bfbits(float v){
  __hip_bfloat16 h = __float2bfloat16(v);
  return *(unsigned short*)&h;
}

// C[n,128](bf16 pairs) = act(A[n,128]) @ W[128,128]; act = BN+ReLU if BN.
// 256 thr = 4 waves; block does 128 rows. W in LDS transposed + XOR-swizzled.
template<bool BN>
__global__ __launch_bounds__(256) void k_gemm_mfma(const float* __restrict__ A,
    const float* __restrict__ Wg, const float* __restrict__ coef,
    unsigned int* __restrict__ C, int n){
  __shared__ unsigned short WT[128*128];   // 32 KB
  #pragma unroll
  for (int it = 0; it < 16; ++it){
    int idx = threadIdx.x + 256*it;        // 0..4095 float4s of W
    int k  = idx >> 5;
    int n0 = (idx & 31) * 4;
    float4 wv = *(const float4*)(Wg + (size_t)k*128 + n0);
    unsigned short bb[4] = {bfbits(wv.x), bfbits(wv.y), bfbits(wv.z), bfbits(wv.w)};
    #pragma unroll
    for (int i = 0; i < 4; ++i){
      int col = n0 + i;
      WT[col*128 + (k ^ ((col&7)<<3))] = bb[i];
    }
  }
  __syncthreads();

  int lane = threadIdx.x & 63;
  int wv4  = threadIdx.x >> 6;      // wave 0..3
  int l16  = lane & 15;
  int kg   = lane >> 4;             // 0..3
  int row_base = blockIdx.x*128 + wv4*32;
  int nm1 = n - 1;
  int a0row = min(row_base + l16,      nm1);
  int a1row = min(row_base + 16 + l16, nm1);

  f32x4 acc[2][8] = {};
  #pragma unroll
  for (int k0 = 0; k0 < 128; k0 += 32){
    int k = k0 + kg*8;
    float4 lo0 = *(const float4*)(A + (size_t)a0row*HID + k);
    float4 hi0 = *(const float4*)(A + (size_t)a0row*HID + k + 4);
    float4 lo1 = *(const float4*)(A + (size_t)a1row*HID + k);
    float4 hi1 = *(const float4*)(A + (size_t)a1row*HID + k + 4);
    if (BN){
      float4 sca = *(const float4*)(coef + k);
      float4 scb = *(const float4*)(coef + k + 4);
      float4 sha = *(const float4*)(coef + 128 + k);
      float4 shb = *(const float4*)(coef + 128 + k + 4);
      lo0.x = fmaxf(fmaf(lo0.x, sca.x, sha.x), 0.f);
      lo0.y = fmaxf(fmaf(lo0.y, sca.y, sha.y), 0.f);
      lo0.z = fmaxf(fmaf(lo0.z, sca.z, sha.z), 0.f);
      lo0.w = fmaxf(fmaf(lo0.w, sca.w, sha.w), 0.f);
      hi0.x = fmaxf(fmaf(hi0.x, scb.x, shb.x), 0.f);
      hi0.y = fmaxf(fmaf(hi0.y, scb.y, shb.y), 0.f);
      hi0.z = fmaxf(fmaf(hi0.z, scb.z, shb.z), 0.f);
      hi0.w = fmaxf(fmaf(hi0.w, scb.w, shb.w), 0.f);
      lo1.x = fmaxf(fmaf(lo1.x, sca.x, sha.x), 0.f);
      lo1.y = fmaxf(fmaf(lo1.y, sca.y, sha.y), 0.f);
      lo1.z = fmaxf(fmaf(lo1.z, sca.z, sha.z), 0.f);
      lo1.w = fmaxf(fmaf(lo1.w, sca.w, sha.w), 0.f);
      hi1.x = fmaxf(fmaf(hi1.x, scb.x, shb.x), 0.f);
      hi1.y = fmaxf(fmaf(hi1.y, scb.y, shb.y), 0.f);
      hi1.z = fmaxf(fmaf(hi1.z, scb.z, shb.z), 0.f);
      hi1.w = fmaxf(fmaf(hi1.w, scb.w, shb.w), 0.f);
    }
    union { bf16x8 v; uint2 u[2]; } a0c, a1c;
    a0c.u[0] = pack_bf16x4(lo0); a0c.u[1] = pack_bf16x4(hi0);
    a1c.u[0] = pack_bf16x4(lo1); a1c.u[1] = pack_bf16x4(hi1);
    bf16x8 a0 = a0c.v, a1 = a1c.v;
    #pragma unroll
    for (int ct = 0; ct < 8; ++ct){
      int col = ct*16 + l16;
      bf16x8 b = *(bf16x8*)&WT[col*128 + (k ^ ((col&7)<<3))];
      acc[0][ct] = __builtin_amdgcn_mfma_f32_16x16x32_bf16(a0, b, acc[0][ct], 0,0,0);
      acc[1][ct] = __builtin_amdgcn_mfma_f32_16x16x32_bf16(a1, b, acc[1][ct], 0,0,0);
    }
  }

  #pragma unroll
  for (int rt = 0; rt < 2; ++rt){
    int growb = row_base + rt*16 + kg*4;
    #pragma unroll
    for (int ct = 0; ct < 8; ++ct){
      #pragma unroll
      for (int r = 0; r < 4; ++r){
        float v = acc[rt][ct][r];
        float o = __shfl_xor(v, 1);
        if (!(lane & 1)){
          int grow = growb + r;
          if (grow < n){
            __hip_bfloat162 p2 = __float22bfloat162_rn({v, o});
            C[(size_t)grow*64 + ct*8 + (l16 >> 1)] = *(unsigned int*)&p2;
          }
        }
      }
    }
  }
}

// ---------------- gather / BN / final ----------------

static __device__ inline float2 bf16pair(unsigned int u){
  __hip_bfloat162 h = *(__hip_bfloat162*)&u;
  return __bfloat1622float2(h);
}

#define GEDGE(ev) { \
  float2 v = bf16pair(xwb[(size_t)(ev).x*64 + lane]); \
  float ww = __int_as_float((ev).y); \
  accx = fmaf(ww, v.x, accx); accy = fmaf(ww, v.y, accy); }

// out[node][:] = bias + dinv^2 * xw[node][:] + sum_j w_j * xw[src_j][:]
// One wave per node, 2 bf16 channels per lane, 8x unrolled (MLP).
__global__ __launch_bounds__(256) void k_gather128(const unsigned int* __restrict__ xwb,
    const int2* __restrict__ csr,
    const int* __restrict__ rowptr, const int* __restrict__ cnt,
    const float* __restrict__ dinv, const float* __restrict__ bias,
    float* __restrict__ out, int n){
  int node = blockIdx.x*4 + (threadIdx.x >> 6);
  int lane = threadIdx.x & 63;
  if (node >= n) return;
  int j = rowptr[node];
  int m = cnt[node];
  int end = j + m;
  float di = dinv[node];
  float2 b = *(const float2*)(bias + lane*2);
  float2 self = bf16pair(xwb[(size_t)node*64 + lane]);
  float sw = di * di;
  float accx = fmaf(sw, self.x, b.x);
  float accy = fmaf(sw, self.y, b.y);
  for (; j + 8 <= end; j += 8){
    int2 e0 = csr[j+0], e1 = csr[j+1], e2 = csr[j+2], e3 = csr[j+3];
    int2 e4 = csr[j+4], e5 = csr[j+5], e6 = csr[j+6], e7 = csr[j+7];
    unsigned int u0 = xwb[(size_t)e0.x*64 + lane];
    unsigned int u1 = xwb[(size_t)e1.x*64 + lane];
    unsigned int u2 = xwb[(size_t)e2.x*64 + lane];
    unsigned int u3 = xwb[(size_t)e3.x*64 + lane];
    unsigned int u4 = xwb[(size_t)e4.x*64 + lane];
    unsigned int u5 = xwb[(size_t)e5.x*64 + lane];
    unsigned int u6 = xwb[(size_t)e6.x*64 + lane];
    unsigned int u7 = xwb[(size_t)e7.x*64 + lane];
    float2 v0 = bf16pair(u0), v1 = bf16pair(u1), v2 = bf16pair(u2), v3 = bf16pair(u3);
    float2 v4 = bf16pair(u4), v5 = bf16pair(u5), v6 = bf16pair(u6), v7 = bf16pair(u7);
    float w0 = __int_as_float(e0.y), w1 = __int_as_float(e1.y);
    float w2 = __int_as_float(e2.y), w3 = __int_as_float(e3.y);
    float w4 = __int_as_float(e4.y), w5 = __int_as_float(e5.y);
    float w6 = __int_as_float(e6.y), w7 = __int_as_float(e7.y);
    accx = fmaf(w0, v0.x, accx); accy = fmaf(w0, v0.y, accy);
    accx = fmaf(w1, v1.x, accx); accy = fmaf(w1, v1.y, accy);
    accx = fmaf(w2, v2.x, accx); accy = fmaf(w2, v2.y, accy);
    accx = fmaf(w3, v3.x, accx); accy = fmaf(w3, v3.y, accy);
    accx = fmaf(w4, v4.x, accx); accy = fmaf(w4, v4.y, accy);
    accx = fmaf(w5, v5.x, accx); accy = fmaf(w5, v5.y, accy);
    accx = fmaf(w6, v6.x, accx); accy = fmaf(w6, v6.y, accy);
    accx = fmaf(w7, v7.x, accx); accy = fmaf(w7, v7.y, accy);
  }
  if (j + 4 <= end){
    int2 e0 = csr[j+0], e1 = csr[j+1], e2 = csr[j+2], e3 = csr[j+3];
    unsigned int u0 = xwb[(size_t)e0.x*64 + lane];
    unsigned int u1 = xwb[(size_t)e1.x*64 + lane];
    unsigned int u2 = xwb[(size_t)e2.x*64 + lane];
    unsigned int u3 = xwb[(size_t)e3.x*64 + lane];
    float2 v0 = bf16pair(u0), v1 = bf16pair(u1), v2 = bf16pair(u2), v3 = bf16pair(u3);
    float w0 = __int_as_float(e0.y), w1 = __int_as_float(e1.y);
    float w2 = __int_as_float(e2.y), w3 = __int_as_float(e3.y);
    accx = fmaf(w0, v0.x, accx); accy = fmaf(w0, v0.y, accy);
    accx = fmaf(w1, v1.x, accx); accy = fmaf(w1, v1.y, accy);
    accx = fmaf(w2, v2.x, accx); accy = fmaf(w2, v2.y, accy);
    accx = fmaf(w3, v3.x, accx); accy = fmaf(w3, v3.y, accy);
    j += 4;
  }
  if (j + 2 <= end){
    int2 e0 = csr[j+0], e1 = csr[j+1];
    GEDGE(e0); GEDGE(e1);
    j += 2;
  }
  if (j < end){
    int2 e0 = csr[j];
    GEDGE(e0);
  }
  float2 r; r.x = accx; r.y = accy;
  *(float2*)(out + (size_t)node*HID + lane*2) = r;
}

__global__ __launch_bounds__(256) void k_bnstats(const float* __restrict__ h,
                                                 float* stats, int n){
  __shared__ float ls[256], lq[256];
  int c = threadIdx.x & 127;
  int r0 = blockIdx.x*2 + (threadIdx.x >> 7);
  float s = 0.f, q = 0.f;
  for (int r = r0; r < n; r += gridDim.x*2){
    float v = h[(size_t)r*HID + c];
    s += v;
    q = fmaf(v, v, q);
  }
  ls[threadIdx.x] = s; lq[threadIdx.x] = q;
  __syncthreads();
  if (threadIdx.x < 128){
    s = ls[threadIdx.x] + ls[threadIdx.x + 128];
    q = lq[threadIdx.x] + lq[threadIdx.x + 128];
    atomicAdd(&stats[c], s);
    atomicAdd(&stats[128 + c], q);
  }
}

__global__ void k_bnfin(const float* __restrict__ stats, const float* __restrict__ gamma,
                        const float* __restrict__ beta, float* coef, int n){
  int c = threadIdx.x;  // 128 threads
  float inv_n = 1.0f / (float)n;
  float mean = stats[c] * inv_n;
  float var = fmaxf(stats[128 + c] * inv_n - mean*mean, 0.f);
  float sc = gamma[c] / sqrtf(var + BN_EPS);
  coef[c] = sc;
  coef[128 + c] = fmaf(-mean, sc, beta[c]);
}

__global__ __launch_bounds__(256) void k_dotW3(const float* __restrict__ h,
    const float* __restrict__ coef, const float* __restrict__ W3,
    float* __restrict__ xw3, int n){
  int lane = threadIdx.x & 31;
  int row = blockIdx.x*8 + (threadIdx.x >> 5);
  if (row >= n) return;
  float4 v  = *(const float4*)(h + (size_t)row*HID + lane*4);
  float4 sc = *(const float4*)(coef + lane*4);
  float4 sh = *(const float4*)(coef + 128 + lane*4);
  float4 w  = *(const float4*)(W3 + lane*4);
  float acc = fmaxf(fmaf(v.x, sc.x, sh.x), 0.f) * w.x
            + fmaxf(fmaf(v.y, sc.y, sh.y), 0.f) * w.y
            + fmaxf(fmaf(v.z, sc.z, sh.z), 0.f) * w.z
            + fmaxf(fmaf(v.w, sc.w, sh.w), 0.f) * w.w;
  #pragma unroll
  for (int m = 1; m < 32; m <<= 1) acc += __shfl_xor(acc, m, 32);
  if (lane == 0) xw3[row] = acc;
}

__global__ void k_gather1(const float* __restrict__ xw3, const int2* __restrict__ csr,
    const int* __restrict__ rowptr,
    const int* __restrict__ cnt, const float* __restrict__ dinv,
    const float* __restrict__ b3, float* __restrict__ out, int n){
  int i = blockIdx.x*256 + threadIdx.x;
  if (i >= n) return;
  float di = dinv[i];
  float acc = fmaf(di*di, xw3[i], b3[0]);
  int s = rowptr[i], m = cnt[i];
  for (int j = 0; j < m; ++j){
    int2 e = csr[s + j];
    acc = fmaf(__int_as_float(e.y), xw3[e.x], acc);
  }
  out[i] = acc;
}

extern "C" void kernel_launch(void* const* d_in, const int* in_sizes, int n_in,
                              void* d_out, int out_size, void* d_ws, size_t ws_size,
                              hipStream_t stream){
  const float* x    = (const float*)d_in[0];
  const int*   ei   = (const int*)  d_in[1];
  const float* attr = (const float*)d_in[2];
  const float* W1   = (const float*)d_in[3];
  const float* b1   = (const float*)d_in[4];
  const float* g1   = (const float*)d_in[5];
  const float* be1  = (const float*)d_in[6];
  const float* W2   = (const float*)d_in[7];
  const float* b2   = (const float*)d_in[8];
  const float* g2   = (const float*)d_in[9];
  const float* be2  = (const float*)d_in[10];
  const float* W3   = (const float*)d_in[11];
  const float* b3   = (const float*)d_in[12];
  float* out = (float*)d_out;

  const int N = in_sizes[0] / HID;   // 100000
  const int E = in_sizes[2];         // 1600000
  const int N8 = 8*N;

  char* w = (char*)d_ws;
  auto take = [&](size_t bytes) -> char* { char* p = w; w += alignup(bytes); return p; };
  unsigned long long* hist = (unsigned long long*)take((size_t)N8*8);
  int*   ptrT   = (int*)  take(((size_t)N8+1)*4);
  int*   cursorT= (int*)  take((size_t)N8*4);
  float* dinv   = (float*)take((size_t)N*4);
  int*   cnt    = (int*)  take((size_t)N*4);
  int*   rowptr = (int*)  take((size_t)N*4);
  int*   bsumA  = (int*)  take(512*4);
  int*   bsumB  = (int*)  take(4096*4);
  float* stats  = (float*)take(256*4);
  float* coef1  = (float*)take(256*4);
  float* coef2  = (float*)take(256*4);
  int2*  tempcsr= (int2*) take((size_t)E*8);
  int2*  csr    = (int2*) take((size_t)E*8);
  float* xw3    = (float*)take((size_t)N*4);
  unsigned int* bufA = (unsigned int*)take((size_t)N*64*4);  // bf16 pairs [N,64]
  float* bufB   = (float*)take((size_t)N*HID*4);
  (void)ws_size; (void)n_in; (void)out_size;

  int nbN  = (N + 255)/256;    // 391
  int nbE  = (E + 255)/256;    // 6250
  int nbN8 = (N8 + 255)/256;   // 3125
  int nbG  = (N + 127)/128;    // 782 gemm blocks

  // graph preprocessing
  hipMemsetAsync(hist, 0, (size_t)N8*8, stream);
  k_edge_pass1R <<<nbE,  256, 0, stream>>>(ei, attr, hist, N, E);
  k_degcnt      <<<nbN,  256, 0, stream>>>(hist, dinv, cnt, N);
  k_scanA_int   <<<nbN,  256, 0, stream>>>(cnt, rowptr, bsumA, N);
  k_scanB_big   <<<1,    512, 0, stream>>>(bsumA, nbN);
  k_scanC_rowptr<<<nbN,  256, 0, stream>>>(rowptr, bsumA, N);
  k_scanA_hist  <<<nbN8, 256, 0, stream>>>(hist, ptrT, bsumB, N8);
  k_scanB_big   <<<1,    512, 0, stream>>>(bsumB, nbN8);
  k_scanC_temp  <<<nbN8, 256, 0, stream>>>(ptrT, cursorT, bsumB, N8, E);
  k_fill_temp   <<<nbE,  256, 0, stream>>>(ei, attr, dinv, cursorT, tempcsr, N, E);
  k_permute     <<<(N+31)/32, 256, 0, stream>>>(tempcsr, ptrT, rowptr, csr, N);

  // layer 1
  k_gemm_mfma<false><<<nbG, 256, 0, stream>>>(x, W1, nullptr, bufA, N);
  k_gather128       <<<(N+3)/4, 256, 0, stream>>>(bufA, csr, rowptr, cnt, dinv, b1, bufB, N);
  hipMemsetAsync(stats, 0, 256*4, stream);
  k_bnstats         <<<512, 256, 0, stream>>>(bufB, stats, N);
  k_bnfin           <<<1, 128, 0, stream>>>(stats, g1, be1, coef1, N);

  // layer 2 (BN1+ReLU fused into gemm A-load)
  k_gemm_mfma<true> <<<nbG, 256, 0, stream>>>(bufB, W2, coef1, bufA, N);
  k_gather128       <<<(N+3)/4, 256, 0, stream>>>(bufA, csr, rowptr, cnt, dinv, b2, bufB, N);
  hipMemsetAsync(stats, 0, 256*4, stream);
  k_bnstats         <<<512, 256, 0, stream>>>(bufB, stats, N);
  k_bnfin           <<<1, 128, 0, stream>>>(stats, g2, be2, coef2, N);

  // layer 3 (BN2+ReLU fused into the 128->1 dot)
  k_dotW3           <<<(N+7)/8, 256, 0, stream>>>(bufB, coef2, W3, xw3, N);
  k_gather1         <<<nbN, 256, 0, stream>>>(xw3, csr, rowptr, cnt, dinv, b3, out, N);
}

// Round 8
// 459.207 us; speedup vs baseline: 1.0553x; 1.0553x over previous
//
#include <hip/hip_runtime.h>
#include <hip/hip_bf16.h>

// GCN 3-layer forward, MI355X. Round 8 (= r7 design, compile fix):
//  - r7's FMA8 macro parameter `w` collided with the `.w` member access
//    ((v).w -> (va).wa). Replaced with an inline function.
//  - Single-pass fill, node-major CSR, per-replica in-node cursors (r5).
//  - Fat kernel: gemm1 co-launched with edge_pass1R (MFMA hides under the
//    fabric-atomic-bound edge pass).
//  - degcnt + scanA fused.
//  - Gather: 16 lanes x 16B (uint4) per feature row, 4 edge-groups per wave,
//    2-deep unroll, shfl_xor cross-group reduction.

#define HID 128
#define BN_EPS 1e-5f

typedef __attribute__((ext_vector_type(8))) short bf16x8;
typedef __attribute__((ext_vector_type(4))) float f32x4;

static inline size_t alignup(size_t x){ return (x + 255) & ~(size_t)255; }

// ---------------- graph preprocessing ----------------

__device__ inline void pass1_body(const int* __restrict__ ei, const float* __restrict__ attr,
                                  unsigned long long* __restrict__ hist, int N, int E,
                                  int bid){
  int e = bid*256 + threadIdx.x;
  if (e >= E) return;
  int r = bid & 7;
  int dst = ei[E + e];
  unsigned long long pk = (1ULL << 40)
                        + (unsigned long long)((double)attr[e] * 4294967296.0);
  atomicAdd(&hist[(size_t)r*N + dst], pk);
}

// dinv + cnt + block-local exclusive scan of cnt (fused degcnt+scanA)
__global__ void k_degscan(const unsigned long long* __restrict__ hist,
                          float* __restrict__ dinv, int* __restrict__ cnt,
                          int* rowptr, int* bsum, int N){
  __shared__ int tmp[256];
  int i = blockIdx.x*256 + threadIdx.x;
  int c = 0;
  if (i < N){
    unsigned long long wsum = 0;
    #pragma unroll
    for (int r = 0; r < 8; ++r){
      unsigned long long h = hist[(size_t)r*N + i];
      wsum += h & ((1ULL << 40) - 1);
      c += (int)(h >> 40);
    }
    float deg = 1.0f + (float)((double)wsum * 2.3283064365386963e-10);  // *2^-32
    dinv[i] = 1.0f / sqrtf(deg);
    cnt[i] = c;
  }
  tmp[threadIdx.x] = c;
  __syncthreads();
  #pragma unroll
  for (int d = 1; d < 256; d <<= 1){
    int t = (threadIdx.x >= d) ? tmp[threadIdx.x - d] : 0;
    __syncthreads();
    tmp[threadIdx.x] += t;
    __syncthreads();
  }
  if (i < N) rowptr[i] = tmp[threadIdx.x] - c;   // exclusive within block
  if (threadIdx.x == 255) bsum[blockIdx.x] = tmp[255];
}

__global__ void k_scanB(int* bsum, int nb){
  __shared__ int tmp[512];
  int v = (threadIdx.x < nb) ? bsum[threadIdx.x] : 0;
  tmp[threadIdx.x] = v;
  __syncthreads();
  #pragma unroll
  for (int d = 1; d < 512; d <<= 1){
    int t = (threadIdx.x >= d) ? tmp[threadIdx.x - d] : 0;
    __syncthreads();
    tmp[threadIdx.x] += t;
    __syncthreads();
  }
  if (threadIdx.x < nb) bsum[threadIdx.x] = tmp[threadIdx.x] - v;
}

__global__ void k_scanC_cursor(int* rowptr, const int* __restrict__ bsum,
                               const unsigned long long* __restrict__ hist,
                               int* __restrict__ cursorR, int N){
  int i = blockIdx.x*256 + threadIdx.x;
  if (i >= N) return;
  int v = rowptr[i] + bsum[blockIdx.x];
  rowptr[i] = v;
  int running = v;
  #pragma unroll
  for (int r = 0; r < 8; ++r){
    cursorR[(size_t)r*N + i] = running;
    running += (int)(hist[(size_t)r*N + i] >> 40);
  }
}

__global__ void k_fill(const int* __restrict__ ei, const float* __restrict__ attr,
                       const float* __restrict__ dinv, int* __restrict__ cursorR,
                       int2* __restrict__ csr, int N, int E){
  int e = blockIdx.x*256 + threadIdx.x;
  if (e >= E) return;
  int r = blockIdx.x & 7;
  int src = ei[e];
  int dst = ei[E + e];
  int pos = atomicAdd(&cursorR[(size_t)r*N + dst], 1);
  float w = dinv[src] * attr[e] * dinv[dst];
  csr[pos] = make_int2(src, __float_as_int(w));
}

// ---------------- MFMA GEMM ----------------

static __device__ inline uint2 pack_bf16x4(float4 a){
  __hip_bfloat162 lo = __float22bfloat162_rn({a.x, a.y});
  __hip_bfloat162 hi = __float22bfloat162_rn({a.z, a.w});
  uint2 r;
  r.x = *(unsigned int*)&lo;
  r.y = *(unsigned int*)&hi;
  return r;
}

static __device__ inline unsigned short bfbits(float v){
  __hip_bfloat16 h = __float2bfloat16(v);
  return *(unsigned short*)&h;
}

// C[n,128](bf16 pairs) = act(A[n,128]) @ W[128,128]; act = BN+ReLU if BN.
// 256 thr = 4 waves; block does 128 rows. W in LDS transposed + XOR-swizzled.
template<bool BN>
__device__ inline void gemm_body(unsigned short* WT, const float* __restrict__ A,
    const float* __restrict__ Wg, const float* __restrict__ coef,
    unsigned int* __restrict__ C, int n, int bid){
  #pragma unroll
  for (int it = 0; it < 16; ++it){
    int idx = threadIdx.x + 256*it;        // 0..4095 float4s of W
    int k  = idx >> 5;
    int n0 = (idx & 31) * 4;
    float4 wv = *(const float4*)(Wg + (size_t)k*128 + n0);
    unsigned short bb[4] = {bfbits(wv.x), bfbits(wv.y), bfbits(wv.z), bfbits(wv.w)};
    #pragma unroll
    for (int i = 0; i < 4; ++i){
      int col = n0 + i;
      WT[col*128 + (k ^ ((col&7)<<3))] = bb[i];
    }
  }
  __syncthreads();

  int lane = threadIdx.x & 63;
  int wv4  = threadIdx.x >> 6;      // wave 0..3
  int l16  = lane & 15;
  int kg   = lane >> 4;             // 0..3
  int row_base = bid*128 + wv4*32;
  int nm1 = n - 1;
  int a0row = min(row_base + l16,      nm1);
  int a1row = min(row_base + 16 + l16, nm1);

  f32x4 acc[2][8] = {};
  #pragma unroll
  for (int k0 = 0; k0 < 128; k0 += 32){
    int k = k0 + kg*8;
    float4 lo0 = *(const float4*)(A + (size_t)a0row*HID + k);
    float4 hi0 = *(const float4*)(A + (size_t)a0row*HID + k + 4);
    float4 lo1 = *(const float4*)(A + (size_t)a1row*HID + k);
    float4 hi1 = *(const float4*)(A + (size_t)a1row*HID + k + 4);
    if (BN){
      float4 sca = *(const float4*)(coef + k);
      float4 scb = *(const float4*)(coef + k + 4);
      float4 sha = *(const float4*)(coef + 128 + k);
      float4 shb = *(const float4*)(coef + 128 + k + 4);
      lo0.x = fmaxf(fmaf(lo0.x, sca.x, sha.x), 0.f);
      lo0.y = fmaxf(fmaf(lo0.y, sca.y, sha.y), 0.f);
      lo0.z = fmaxf(fmaf(lo0.z, sca.z, sha.z), 0.f);
      lo0.w = fmaxf(fmaf(lo0.w, sca.w, sha.w), 0.f);
      hi0.x = fmaxf(fmaf(hi0.x, scb.x, shb.x), 0.f);
      hi0.y = fmaxf(fmaf(hi0.y, scb.y, shb.y), 0.f);
      hi0.z = fmaxf(fmaf(hi0.z, scb.z, shb.z), 0.f);
      hi0.w = fmaxf(fmaf(hi0.w, scb.w, shb.w), 0.f);
      lo1.x = fmaxf(fmaf(lo1.x, sca.x, sha.x), 0.f);
      lo1.y = fmaxf(fmaf(lo1.y, sca.y, sha.y), 0.f);
      lo1.z = fmaxf(fmaf(lo1.z, sca.z, sha.z), 0.f);
      lo1.w = fmaxf(fmaf(lo1.w, sca.w, sha.w), 0.f);
      hi1.x = fmaxf(fmaf(hi1.x, scb.x, shb.x), 0.f);
      hi1.y = fmaxf(fmaf(hi1.y, scb.y, shb.y), 0.f);
      hi1.z = fmaxf(fmaf(hi1.z, scb.z, shb.z), 0.f);
      hi1.w = fmaxf(fmaf(hi1.w, scb.w, shb.w), 0.f);
    }
    union { bf16x8 v; uint2 u[2]; } a0c, a1c;
    a0c.u[0] = pack_bf16x4(lo0); a0c.u[1] = pack_bf16x4(hi0);
    a1c.u[0] = pack_bf16x4(lo1); a1c.u[1] = pack_bf16x4(hi1);
    bf16x8 a0 = a0c.v, a1 = a1c.v;
    #pragma unroll
    for (int ct = 0; ct < 8; ++ct){
      int col = ct*16 + l16;
      bf16x8 b = *(bf16x8*)&WT[col*128 + (k ^ ((col&7)<<3))];
      acc[0][ct] = __builtin_amdgcn_mfma_f32_16x16x32_bf16(a0, b, acc[0][ct], 0,0,0);
      acc[1][ct] = __builtin_amdgcn_mfma_f32_16x16x32_bf16(a1, b, acc[1][ct], 0,0,0);
    }
  }

  #pragma unroll
  for (int rt = 0; rt < 2; ++rt){
    int growb = row_base + rt*16 + kg*4;
    #pragma unroll
    for (int ct = 0; ct < 8; ++ct){
      #pragma unroll
      for (int r = 0; r < 4; ++r){
        float v = acc[rt][ct][r];
        float o = __shfl_xor(v, 1);
        if (!(lane & 1)){
          int grow = growb + r;
          if (grow < n){
            __hip_bfloat162 p2 = __float22bfloat162_rn({v, o});
            C[(size_t)grow*64 + ct*8 + (l16 >> 1)] = *(unsigned int*)&p2;
          }
        }
      }
    }
  }
}

// fat kernel: blocks [0,nbE) do edge pass1; [nbE, nbE+nbG) do gemm1 (no BN).
__global__ __launch_bounds__(256) void k_pass1_gemm(
    const int* __restrict__ ei, const float* __restrict__ attr,
    unsigned long long* __restrict__ hist, int N, int E, int nbE,
    const float* __restrict__ A, const float* __restrict__ Wg,
    unsigned int* __restrict__ C, int n){
  __shared__ unsigned short WT[128*128];   // 32 KB (gemm path only)
  int bid = blockIdx.x;
  if (bid < nbE){
    pass1_body(ei, attr, hist, N, E, bid);
  } else {
    gemm_body<false>(WT, A, Wg, nullptr, C, n, bid - nbE);
  }
}

__global__ __launch_bounds__(256) void k_gemm_mfma_bn(const float* __restrict__ A,
    const float* __restrict__ Wg, const float* __restrict__ coef,
    unsigned int* __restrict__ C, int n){
  __shared__ unsigned short WT[128*128];
  gemm_body<true>(WT, A, Wg, coef, C, n, blockIdx.x);
}

// ---------------- gather / BN / final ----------------

static __device__ inline float2 bf16pair(unsigned int u){
  __hip_bfloat162 h = *(__hip_bfloat162*)&u;
  return __bfloat1622float2(h);
}

struct Acc8 { float a0,a1,a2,a3,a4,a5,a6,a7; };

static __device__ inline void fma8(Acc8& a, uint4 v, float wt){
  float2 p0 = bf16pair(v.x), p1 = bf16pair(v.y);
  float2 p2 = bf16pair(v.z), p3 = bf16pair(v.w);
  a.a0 = fmaf(wt, p0.x, a.a0); a.a1 = fmaf(wt, p0.y, a.a1);
  a.a2 = fmaf(wt, p1.x, a.a2); a.a3 = fmaf(wt, p1.y, a.a3);
  a.a4 = fmaf(wt, p2.x, a.a4); a.a5 = fmaf(wt, p2.y, a.a5);
  a.a6 = fmaf(wt, p3.x, a.a6); a.a7 = fmaf(wt, p3.y, a.a7);
}

// out[node][:] = bias + dinv^2*xw[node][:] + sum_j w_j*xw[src_j][:]
// One wave per node: 4 groups of 16 lanes; group g walks edges g, g+4, g+8,...
// Each lane loads 16B (8 bf16 channels) per edge. Cross-group shfl_xor
// reduction; group 0 adds self+bias and stores.
__global__ __launch_bounds__(256) void k_gather128(const unsigned int* __restrict__ xwb,
    const int2* __restrict__ csr,
    const int* __restrict__ rowptr, const int* __restrict__ cnt,
    const float* __restrict__ dinv, const float* __restrict__ bias,
    float* __restrict__ out, int n){
  int node = blockIdx.x*4 + (threadIdx.x >> 6);
  int lane = threadIdx.x & 63;
  if (node >= n) return;
  int l16 = lane & 15;
  int eg  = lane >> 4;
  int base = rowptr[node];
  int m = cnt[node];
  Acc8 a = {0,0,0,0,0,0,0,0};
  if (eg == 0){
    float di = dinv[node];
    float sw = di * di;
    uint4 sv = *(const uint4*)(xwb + (size_t)node*64 + l16*4);
    float4 b0 = *(const float4*)(bias + l16*8);
    float4 b1 = *(const float4*)(bias + l16*8 + 4);
    a.a0 = b0.x; a.a1 = b0.y; a.a2 = b0.z; a.a3 = b0.w;
    a.a4 = b1.x; a.a5 = b1.y; a.a6 = b1.z; a.a7 = b1.w;
    fma8(a, sv, sw);
  }
  int j = eg;
  for (; j + 4 < m; j += 8){
    int2 ea = csr[base + j];
    int2 eb = csr[base + j + 4];
    uint4 va = *(const uint4*)(xwb + (size_t)ea.x*64 + l16*4);
    uint4 vb = *(const uint4*)(xwb + (size_t)eb.x*64 + l16*4);
    fma8(a, va, __int_as_float(ea.y));
    fma8(a, vb, __int_as_float(eb.y));
  }
  if (j < m){
    int2 ea = csr[base + j];
    uint4 va = *(const uint4*)(xwb + (size_t)ea.x*64 + l16*4);
    fma8(a, va, __int_as_float(ea.y));
  }
  // reduce across the 4 edge-groups
  a.a0 += __shfl_xor(a.a0, 16); a.a1 += __shfl_xor(a.a1, 16);
  a.a2 += __shfl_xor(a.a2, 16); a.a3 += __shfl_xor(a.a3, 16);
  a.a4 += __shfl_xor(a.a4, 16); a.a5 += __shfl_xor(a.a5, 16);
  a.a6 += __shfl_xor(a.a6, 16); a.a7 += __shfl_xor(a.a7, 16);
  a.a0 += __shfl_xor(a.a0, 32); a.a1 += __shfl_xor(a.a1, 32);
  a.a2 += __shfl_xor(a.a2, 32); a.a3 += __shfl_xor(a.a3, 32);
  a.a4 += __shfl_xor(a.a4, 32); a.a5 += __shfl_xor(a.a5, 32);
  a.a6 += __shfl_xor(a.a6, 32); a.a7 += __shfl_xor(a.a7, 32);
  if (eg == 0){
    float4 r0; r0.x=a.a0; r0.y=a.a1; r0.z=a.a2; r0.w=a.a3;
    float4 r1; r1.x=a.a4; r1.y=a.a5; r1.z=a.a6; r1.w=a.a7;
    *(float4*)(out + (size_t)node*HID + l16*8)     = r0;
    *(float4*)(out + (size_t)node*HID + l16*8 + 4) = r1;
  }
}

__global__ __launch_bounds__(256) void k_bnstats(const float* __restrict__ h,
                                                 float* stats, int n){
  __shared__ float ls[256], lq[256];
  int c = threadIdx.x & 127;
  int r0 = blockIdx.x*2 + (threadIdx.x >> 7);
  float s = 0.f, q = 0.f;
  for (int r = r0; r < n; r += gridDim.x*2){
    float v = h[(size_t)r*HID + c];
    s += v;
    q = fmaf(v, v, q);
  }
  ls[threadIdx.x] = s; lq[threadIdx.x] = q;
  __syncthreads();
  if (threadIdx.x < 128){
    s = ls[threadIdx.x] + ls[threadIdx.x + 128];
    q = lq[threadIdx.x] + lq[threadIdx.x + 128];
    atomicAdd(&stats[c], s);
    atomicAdd(&stats[128 + c], q);
  }
}

__global__ void k_bnfin(const float* __restrict__ stats, const float* __restrict__ gamma,
                        const float* __restrict__ beta, float* coef, int n){
  int c = threadIdx.x;  // 128 threads
  float inv_n = 1.0f / (float)n;
  float mean = stats[c] * inv_n;
  float var = fmaxf(stats[128 + c] * inv_n - mean*mean, 0.f);
  float sc = gamma[c] / sqrtf(var + BN_EPS);
  coef[c] = sc;
  coef[128 + c] = fmaf(-mean, sc, beta[c]);
}

__global__ __launch_bounds__(256) void k_dotW3(const float* __restrict__ h,
    const float* __restrict__ coef, const float* __restrict__ W3,
    float* __restrict__ xw3, int n){
  int lane = threadIdx.x & 31;
  int row = blockIdx.x*8 + (threadIdx.x >> 5);
  if (row >= n) return;
  float4 v  = *(const float4*)(h + (size_t)row*HID + lane*4);
  float4 sc = *(const float4*)(coef + lane*4);
  float4 sh = *(const float4*)(coef + 128 + lane*4);
  float4 w  = *(const float4*)(W3 + lane*4);
  float acc = fmaxf(fmaf(v.x, sc.x, sh.x), 0.f) * w.x
            + fmaxf(fmaf(v.y, sc.y, sh.y), 0.f) * w.y
            + fmaxf(fmaf(v.z, sc.z, sh.z), 0.f) * w.z
            + fmaxf(fmaf(v.w, sc.w, sh.w), 0.f) * w.w;
  #pragma unroll
  for (int m = 1; m < 32; m <<= 1) acc += __shfl_xor(acc, m, 32);
  if (lane == 0) xw3[row] = acc;
}

__global__ void k_gather1(const float* __restrict__ xw3, const int2* __restrict__ csr,
    const int* __restrict__ rowptr,
    const int* __restrict__ cnt, const float* __restrict__ dinv,
    const float* __restrict__ b3, float* __restrict__ out, int n){
  int i = blockIdx.x*256 + threadIdx.x;
  if (i >= n) return;
  float di = dinv[i];
  float acc = fmaf(di*di, xw3[i], b3[0]);
  int s = rowptr[i], m = cnt[i];
  for (int j = 0; j < m; ++j){
    int2 e = csr[s + j];
    acc = fmaf(__int_as_float(e.y), xw3[e.x], acc);
  }
  out[i] = acc;
}

extern "C" void kernel_launch(void* const* d_in, const int* in_sizes, int n_in,
                              void* d_out, int out_size, void* d_ws, size_t ws_size,
                              hipStream_t stream){
  const float* x    = (const float*)d_in[0];
  const int*   ei   = (const int*)  d_in[1];
  const float* attr = (const float*)d_in[2];
  const float* W1   = (const float*)d_in[3];
  const float* b1   = (const float*)d_in[4];
  const float* g1   = (const float*)d_in[5];
  const float* be1  = (const float*)d_in[6];
  const float* W2   = (const float*)d_in[7];
  const float* b2   = (const float*)d_in[8];
  const float* g2   = (const float*)d_in[9];
  const float* be2  = (const float*)d_in[10];
  const float* W3   = (const float*)d_in[11];
  const float* b3   = (const float*)d_in[12];
  float* out = (float*)d_out;

  const int N = in_sizes[0] / HID;   // 100000
  const int E = in_sizes[2];         // 1600000

  char* w = (char*)d_ws;
  auto take = [&](size_t bytes) -> char* { char* p = w; w += alignup(bytes); return p; };
  unsigned long long* hist = (unsigned long long*)take((size_t)8*N*8);
  int*   cursorR= (int*)  take((size_t)8*N*4);
  float* dinv   = (float*)take((size_t)N*4);
  int*   cnt    = (int*)  take((size_t)N*4);
  int*   rowptr = (int*)  take((size_t)N*4);
  int*   bsum   = (int*)  take(512*4);
  float* stats  = (float*)take(256*4);
  float* coef1  = (float*)take(256*4);
  float* coef2  = (float*)take(256*4);
  int2*  csr    = (int2*) take((size_t)E*8);
  float* xw3    = (float*)take((size_t)N*4);
  unsigned int* bufA = (unsigned int*)take((size_t)N*64*4);  // bf16 pairs [N,64]
  float* bufB   = (float*)take((size_t)N*HID*4);
  (void)ws_size; (void)n_in; (void)out_size;

  int nbN = (N + 255)/256;   // 391
  int nbE = (E + 255)/256;   // 6250
  int nbG = (N + 127)/128;   // 782 gemm blocks

  // preprocessing + gemm1 overlapped in one fat kernel
  hipMemsetAsync(hist, 0, (size_t)8*N*8, stream);
  k_pass1_gemm  <<<nbE + nbG, 256, 0, stream>>>(ei, attr, hist, N, E, nbE,
                                                x, W1, bufA, N);
  k_degscan     <<<nbN, 256, 0, stream>>>(hist, dinv, cnt, rowptr, bsum, N);
  k_scanB       <<<1,   512, 0, stream>>>(bsum, nbN);
  k_scanC_cursor<<<nbN, 256, 0, stream>>>(rowptr, bsum, hist, cursorR, N);
  k_fill        <<<nbE, 256, 0, stream>>>(ei, attr, dinv, cursorR, csr, N, E);

  // layer 1 (gemm1 already done in fat kernel)
  k_gather128   <<<(N+3)/4, 256, 0, stream>>>(bufA, csr, rowptr, cnt, dinv, b1, bufB, N);
  hipMemsetAsync(stats, 0, 256*4, stream);
  k_bnstats     <<<512, 256, 0, stream>>>(bufB, stats, N);
  k_bnfin       <<<1, 128, 0, stream>>>(stats, g1, be1, coef1, N);

  // layer 2 (BN1+ReLU fused into gemm A-load)
  k_gemm_mfma_bn<<<nbG, 256, 0, stream>>>(bufB, W2, coef1, bufA, N);
  k_gather128   <<<(N+3)/4, 256, 0, stream>>>(bufA, csr, rowptr, cnt, dinv, b2, bufB, N);
  hipMemsetAsync(stats, 0, 256*4, stream);
  k_bnstats     <<<512, 256, 0, stream>>>(bufB, stats, N);
  k_bnfin       <<<1, 128, 0, stream>>>(stats, g2, be2, coef2, N);

  // layer 3 (BN2+ReLU fused into the 128->1 dot)
  k_dotW3       <<<(N+7)/8, 256, 0, stream>>>(bufB, coef2, W3, xw3, N);
  k_gather1     <<<nbN, 256, 0, stream>>>(xw3, csr, rowptr, cnt, dinv, b3, out, N);
}